// Round 1
// baseline (220.049 us; speedup 1.0000x reference)
//
#include <hip/hip_runtime.h>

#define NN 8
#define CC 8
#define TT 600
#define FF 257
#define NF (NN * FF)  /* 2056 */
#define LOADING 7.0710678118654746e-04f /* 0.001/sqrt(2) */

// ---------------------------------------------------------------------------
// Kernel 1: partial noise covariance.
// Thread = one (n,f) pair (f innermost -> coalesced), block y = t-chunk.
// Accumulates Hermitian 8x8: 8 real diag + 28 complex upper = 64 floats.
// Writes partial[chunk][j][64]; empty chunks write zeros (ws is poisoned!).
// ---------------------------------------------------------------------------
__global__ __launch_bounds__(256) void cov_kernel(const float* __restrict__ noise,
                                                  float* __restrict__ partial,
                                                  int tc) {
    int j = blockIdx.x * 256 + threadIdx.x;
    if (j >= NF) return;
    int n = j / FF;
    int f = j - n * FF;
    int t0 = blockIdx.y * tc;
    int t1 = t0 + tc;
    if (t1 > TT) t1 = TT;

    const float* base = noise + (size_t)n * (2 * CC * TT * FF) + f;

    float diag[CC];
    float offr[28], offi[28];
#pragma unroll
    for (int c = 0; c < CC; ++c) diag[c] = 0.f;
#pragma unroll
    for (int p = 0; p < 28; ++p) { offr[p] = 0.f; offi[p] = 0.f; }

    for (int t = t0; t < t1; ++t) {
        float vr[CC], vi[CC];
#pragma unroll
        for (int c = 0; c < CC; ++c) {
            vr[c] = base[(c * TT + t) * FF];
            vi[c] = base[((CC + c) * TT + t) * FF];
        }
        int p = 0;
#pragma unroll
        for (int c = 0; c < CC; ++c) {
            diag[c] += vr[c] * vr[c] + vi[c] * vi[c];
#pragma unroll
            for (int d2 = c + 1; d2 < CC; ++d2) {
                // phi[c][d] += v_c * conj(v_d)
                offr[p] += vr[c] * vr[d2] + vi[c] * vi[d2];
                offi[p] += vi[c] * vr[d2] - vr[c] * vi[d2];
                ++p;
            }
        }
    }

    float* o = partial + ((size_t)blockIdx.y * NF + j) * 64;
#pragma unroll
    for (int c = 0; c < CC; ++c) o[c] = diag[c];
#pragma unroll
    for (int p = 0; p < 28; ++p) {
        o[8 + p] = offr[p];
        o[36 + p] = offi[p];
    }
}

// ---------------------------------------------------------------------------
// Kernel 2: reduce partials, add diagonal loading, solve phi x = d
// (unpivoted complex Gaussian elimination — phi is diagonally dominant),
// w = x / (d^H x); store wc = conj(w) interleaved [re,im]*8.
// ---------------------------------------------------------------------------
__global__ __launch_bounds__(64) void solve_kernel(const float* __restrict__ partial,
                                                   const float* __restrict__ steer,
                                                   float* __restrict__ wc,
                                                   int ntc) {
    int j = blockIdx.x * 64 + threadIdx.x;
    if (j >= NF) return;
    int n = j / FF;
    int f = j - n * FF;

    float acc[64];
#pragma unroll
    for (int k = 0; k < 64; ++k) acc[k] = 0.f;
    for (int tci = 0; tci < ntc; ++tci) {
        const float* p = partial + ((size_t)tci * NF + j) * 64;
#pragma unroll
        for (int k = 0; k < 16; ++k) {
            float4 v = ((const float4*)p)[k];
            acc[4 * k + 0] += v.x;
            acc[4 * k + 1] += v.y;
            acc[4 * k + 2] += v.z;
            acc[4 * k + 3] += v.w;
        }
    }

    const float invT = 1.0f / (float)TT;
    float Ar[CC][CC], Ai[CC][CC];
    {
        int p = 0;
#pragma unroll
        for (int c = 0; c < CC; ++c) {
            Ar[c][c] = acc[c] * invT + LOADING;
            Ai[c][c] = LOADING;  // complex diagonal loading -> non-Hermitian
#pragma unroll
            for (int d2 = c + 1; d2 < CC; ++d2) {
                float re = acc[8 + p] * invT, im = acc[36 + p] * invT;
                Ar[c][d2] = re;  Ai[c][d2] = im;
                Ar[d2][c] = re;  Ai[d2][c] = -im;
                ++p;
            }
        }
    }

    float dr[CC], di[CC], br[CC], bi[CC];
#pragma unroll
    for (int c = 0; c < CC; ++c) {
        dr[c] = steer[((n * 2 + 0) * FF + f) * CC + c];
        di[c] = steer[((n * 2 + 1) * FF + f) * CC + c];
        br[c] = dr[c];
        bi[c] = di[c];
    }

    // Gaussian elimination (unit-diagonal scaling), fully unrolled.
#pragma unroll
    for (int k = 0; k < CC; ++k) {
        float ar = Ar[k][k], ai = Ai[k][k];
        float s = 1.0f / (ar * ar + ai * ai);
        float rr = ar * s, ri = -ai * s;
#pragma unroll
        for (int jj = k + 1; jj < CC; ++jj) {
            float xr0 = Ar[k][jj], xi0 = Ai[k][jj];
            Ar[k][jj] = xr0 * rr - xi0 * ri;
            Ai[k][jj] = xr0 * ri + xi0 * rr;
        }
        {
            float xr0 = br[k], xi0 = bi[k];
            br[k] = xr0 * rr - xi0 * ri;
            bi[k] = xr0 * ri + xi0 * rr;
        }
#pragma unroll
        for (int i = k + 1; i < CC; ++i) {
            float mr = Ar[i][k], mi = Ai[i][k];
#pragma unroll
            for (int jj = k + 1; jj < CC; ++jj) {
                float kr = Ar[k][jj], ki = Ai[k][jj];
                Ar[i][jj] -= mr * kr - mi * ki;
                Ai[i][jj] -= mr * ki + mi * kr;
            }
            float bkr = br[k], bki = bi[k];
            br[i] -= mr * bkr - mi * bki;
            bi[i] -= mr * bki + mi * bkr;
        }
    }

    // Back substitution (A now unit upper-triangular).
    float xr[CC], xi[CC];
#pragma unroll
    for (int k = CC - 1; k >= 0; --k) {
        float sr = br[k], si = bi[k];
#pragma unroll
        for (int jj = k + 1; jj < CC; ++jj) {
            sr -= Ar[k][jj] * xr[jj] - Ai[k][jj] * xi[jj];
            si -= Ar[k][jj] * xi[jj] + Ai[k][jj] * xr[jj];
        }
        xr[k] = sr;
        xi[k] = si;
    }

    // deno = d^H x
    float der = 0.f, dei = 0.f;
#pragma unroll
    for (int c = 0; c < CC; ++c) {
        der += dr[c] * xr[c] + di[c] * xi[c];
        dei += dr[c] * xi[c] - dr[c] * 0.f - di[c] * xr[c] + 0.f;  // see below
    }
    // (written explicitly to avoid typos: conj(d)*x = (dr-i di)(xr+i xi))
    // re = dr*xr + di*xi ; im = dr*xi - di*xr   -> recompute im cleanly:
    dei = 0.f;
#pragma unroll
    for (int c = 0; c < CC; ++c) dei += dr[c] * xi[c] - di[c] * xr[c];

    float s = 1.0f / (der * der + dei * dei);
    float* o = wc + (size_t)j * 16;
#pragma unroll
    for (int c = 0; c < CC; ++c) {
        float qr = (xr[c] * der + xi[c] * dei) * s;  // Re(x/deno)
        float qi = (xi[c] * der - xr[c] * dei) * s;  // Im(x/deno)
        o[2 * c] = qr;
        o[2 * c + 1] = -qi;  // conj(w)
    }
}

// ---------------------------------------------------------------------------
// Kernel 3: beamform X[n,t,f] = sum_c wc[n,f,c] * y[n,c,t,f]
// One thread per output element; y coalesced along f, wc L1-cached.
// ---------------------------------------------------------------------------
__global__ __launch_bounds__(256) void bf_kernel(const float* __restrict__ mix,
                                                 const float* __restrict__ wc,
                                                 float* __restrict__ out) {
    int idx = blockIdx.x * 256 + threadIdx.x;
    const int perN = TT * FF;
    if (idx >= NN * perN) return;
    int n = idx / perN;
    int rem = idx - n * perN;
    int t = rem / FF;
    int f = rem - t * FF;

    const float4* w4 = (const float4*)(wc + ((size_t)(n * FF + f)) * 16);
    float4 w0 = w4[0], w1 = w4[1], w2 = w4[2], w3 = w4[3];
    float wr[CC] = {w0.x, w0.z, w1.x, w1.z, w2.x, w2.z, w3.x, w3.z};
    float wi[CC] = {w0.y, w0.w, w1.y, w1.w, w2.y, w2.w, w3.y, w3.w};

    const float* base = mix + (size_t)n * (2 * CC * TT * FF) + t * FF + f;
    float Xr = 0.f, Xi = 0.f;
#pragma unroll
    for (int c = 0; c < CC; ++c) {
        float yr = base[c * TT * FF];
        float yi = base[(CC + c) * TT * FF];
        Xr += wr[c] * yr - wi[c] * yi;
        Xi += wr[c] * yi + wi[c] * yr;
    }
    out[((size_t)(n * 2 + 0) * TT + t) * FF + f] = Xr;
    out[((size_t)(n * 2 + 1) * TT + t) * FF + f] = Xi;
}

extern "C" void kernel_launch(void* const* d_in, const int* in_sizes, int n_in,
                              void* d_out, int out_size, void* d_ws, size_t ws_size,
                              hipStream_t stream) {
    const float* mixture = (const float*)d_in[0];
    const float* noise = (const float*)d_in[1];
    const float* steer = (const float*)d_in[2];
    float* out = (float*)d_out;

    float* partial = (float*)d_ws;
    size_t per_chunk = (size_t)NF * 64 * sizeof(float);
    size_t wc_bytes = (size_t)NF * 16 * sizeof(float);
    int ntc = 25;
    while (ntc > 1 && per_chunk * (size_t)ntc + wc_bytes > ws_size) --ntc;
    int tc = (TT + ntc - 1) / ntc;
    float* wcp = partial + (size_t)ntc * NF * 64;

    dim3 gcov((NF + 255) / 256, ntc);
    cov_kernel<<<gcov, 256, 0, stream>>>(noise, partial, tc);
    solve_kernel<<<(NF + 63) / 64, 64, 0, stream>>>(partial, steer, wcp, ntc);
    int total = NN * TT * FF;
    bf_kernel<<<(total + 255) / 256, 256, 0, stream>>>(mixture, wcp, out);
}

// Round 2
// 211.599 us; speedup vs baseline: 1.0399x; 1.0399x over previous
//
#include <hip/hip_runtime.h>

#define NN 8
#define CC 8
#define TT 600
#define FF 257
#define NF 2056  /* NN * FF */
#define LOADING 7.0710678118654746e-04f /* 0.001/sqrt(2) */

// ---------------------------------------------------------------------------
// Kernel 1: partial noise covariance, 4-wave blocks with LDS tree reduction.
// Block = 256 thr = 4 waves; lane (0..63) -> j = blockIdx.x*64+lane,
// wave (0..3) -> quarter of this block's t-chunk. LDS layout is transposed
// red[k][col] so per-instruction lane stride is 4 B -> conflict-free.
// Writes partial[chunk][j][64] (8 diag + 28 off-re + 28 off-im).
// ---------------------------------------------------------------------------
__global__ __launch_bounds__(256) void cov2_kernel(const float* __restrict__ noise,
                                                   float* __restrict__ partial,
                                                   int tc) {
    __shared__ float red[64][128];  // 32 KB
    int lane = threadIdx.x & 63;
    int wave = threadIdx.x >> 6;
    int j = blockIdx.x * 64 + lane;
    int jc = j < NF ? j : NF - 1;  // clamp: dup lanes compute garbage, never store
    int n = jc / FF;
    int f = jc - n * FF;

    int cend = min((int)(blockIdx.y + 1) * tc, TT);
    int tsub = (tc + 3) >> 2;
    int t0 = blockIdx.y * tc + wave * tsub;
    int t1 = min(t0 + tsub, cend);

    const float* base = noise + (size_t)n * (2 * CC * TT * FF) + f;

    float acc[64];
#pragma unroll
    for (int k = 0; k < 64; ++k) acc[k] = 0.f;

    for (int t = t0; t < t1; ++t) {
        float vr[CC], vi[CC];
#pragma unroll
        for (int c = 0; c < CC; ++c) {
            vr[c] = base[(c * TT + t) * FF];
            vi[c] = base[((CC + c) * TT + t) * FF];
        }
        int p = 0;
#pragma unroll
        for (int c = 0; c < CC; ++c) {
            acc[c] += vr[c] * vr[c] + vi[c] * vi[c];
#pragma unroll
            for (int d2 = c + 1; d2 < CC; ++d2) {
                acc[8 + p] += vr[c] * vr[d2] + vi[c] * vi[d2];       // Re phi[c][d]
                acc[36 + p] += vi[c] * vr[d2] - vr[c] * vi[d2];      // Im phi[c][d]
                ++p;
            }
        }
    }

    // stage 1: waves 2,3 -> LDS; waves 0,1 add
    if (wave >= 2) {
        int col = threadIdx.x - 128;
#pragma unroll
        for (int k = 0; k < 64; ++k) red[k][col] = acc[k];
    }
    __syncthreads();
    if (wave < 2) {
#pragma unroll
        for (int k = 0; k < 64; ++k) acc[k] += red[k][threadIdx.x];
    }
    __syncthreads();
    // stage 2: wave 1 -> LDS; wave 0 adds and stores
    if (wave == 1) {
#pragma unroll
        for (int k = 0; k < 64; ++k) red[k][lane] = acc[k];
    }
    __syncthreads();
    if (wave == 0 && j < NF) {
#pragma unroll
        for (int k = 0; k < 64; ++k) acc[k] += red[k][lane];
        float4* o = (float4*)(partial + ((size_t)blockIdx.y * NF + j) * 64);
#pragma unroll
        for (int k = 0; k < 16; ++k)
            o[k] = make_float4(acc[4 * k], acc[4 * k + 1], acc[4 * k + 2], acc[4 * k + 3]);
    }
}

// ---------------------------------------------------------------------------
// Kernel 2: merged reduce + solve. Block 256 = 4 systems; 64 threads per
// system do a coalesced reduction of the partials (consecutive k ->
// consecutive addresses), then lane 0 of each wave runs the 8x8 complex
// Gaussian elimination (phi is diagonally dominant; unpivoted is safe).
// Stores conj(w) interleaved [re,im]*8 per (n,f).
// ---------------------------------------------------------------------------
__global__ __launch_bounds__(256) void solve2_kernel(const float* __restrict__ partial,
                                                     const float* __restrict__ steer,
                                                     float* __restrict__ wc,
                                                     int ntc) {
    __shared__ float sphi[4][64];
    int k = threadIdx.x & 63;
    int jj = threadIdx.x >> 6;
    int j = blockIdx.x * 4 + jj;  // grid = 514 -> j < 2056 always

    float s = 0.f;
    for (int c = 0; c < ntc; ++c) s += partial[((size_t)c * NF + j) * 64 + k];
    sphi[jj][k] = s;
    __syncthreads();

    if (k != 0) return;
    int n = j / FF;
    int f = j - n * FF;

    const float invT = 1.0f / (float)TT;
    float Ar[CC][CC], Ai[CC][CC];
    {
        int p = 0;
#pragma unroll
        for (int c = 0; c < CC; ++c) {
            Ar[c][c] = sphi[jj][c] * invT + LOADING;
            Ai[c][c] = LOADING;  // complex diagonal loading
#pragma unroll
            for (int d2 = c + 1; d2 < CC; ++d2) {
                float re = sphi[jj][8 + p] * invT, im = sphi[jj][36 + p] * invT;
                Ar[c][d2] = re;  Ai[c][d2] = im;
                Ar[d2][c] = re;  Ai[d2][c] = -im;
                ++p;
            }
        }
    }

    float dr[CC], di[CC], br[CC], bi[CC];
#pragma unroll
    for (int c = 0; c < CC; ++c) {
        dr[c] = steer[((n * 2 + 0) * FF + f) * CC + c];
        di[c] = steer[((n * 2 + 1) * FF + f) * CC + c];
        br[c] = dr[c];
        bi[c] = di[c];
    }

#pragma unroll
    for (int kk = 0; kk < CC; ++kk) {
        float ar = Ar[kk][kk], ai = Ai[kk][kk];
        float sc = 1.0f / (ar * ar + ai * ai);
        float rr = ar * sc, ri = -ai * sc;
#pragma unroll
        for (int c = kk + 1; c < CC; ++c) {
            float xr0 = Ar[kk][c], xi0 = Ai[kk][c];
            Ar[kk][c] = xr0 * rr - xi0 * ri;
            Ai[kk][c] = xr0 * ri + xi0 * rr;
        }
        {
            float xr0 = br[kk], xi0 = bi[kk];
            br[kk] = xr0 * rr - xi0 * ri;
            bi[kk] = xr0 * ri + xi0 * rr;
        }
#pragma unroll
        for (int i = kk + 1; i < CC; ++i) {
            float mr = Ar[i][kk], mi = Ai[i][kk];
#pragma unroll
            for (int c = kk + 1; c < CC; ++c) {
                float kr = Ar[kk][c], ki = Ai[kk][c];
                Ar[i][c] -= mr * kr - mi * ki;
                Ai[i][c] -= mr * ki + mi * kr;
            }
            float bkr = br[kk], bki = bi[kk];
            br[i] -= mr * bkr - mi * bki;
            bi[i] -= mr * bki + mi * bkr;
        }
    }

    float xr[CC], xi[CC];
#pragma unroll
    for (int kk = CC - 1; kk >= 0; --kk) {
        float sr = br[kk], si = bi[kk];
#pragma unroll
        for (int c = kk + 1; c < CC; ++c) {
            sr -= Ar[kk][c] * xr[c] - Ai[kk][c] * xi[c];
            si -= Ar[kk][c] * xi[c] + Ai[kk][c] * xr[c];
        }
        xr[kk] = sr;
        xi[kk] = si;
    }

    // deno = d^H x: re = dr*xr + di*xi ; im = dr*xi - di*xr
    float der = 0.f, dei = 0.f;
#pragma unroll
    for (int c = 0; c < CC; ++c) {
        der += dr[c] * xr[c] + di[c] * xi[c];
        dei += dr[c] * xi[c] - di[c] * xr[c];
    }
    float sc2 = 1.0f / (der * der + dei * dei);
    float* o = wc + (size_t)j * 16;
#pragma unroll
    for (int c = 0; c < CC; ++c) {
        float qr = (xr[c] * der + xi[c] * dei) * sc2;   // Re(w)
        float qi = (xi[c] * der - xr[c] * dei) * sc2;   // Im(w)
        o[2 * c] = qr;
        o[2 * c + 1] = -qi;  // store conj(w)
    }
}

// ---------------------------------------------------------------------------
// Kernel 3: beamform X[n,t,f] = sum_c wc[n,f,c] * y[n,c,t,f]
// One thread per output element; y coalesced along f, wc L1-cached.
// ---------------------------------------------------------------------------
__global__ __launch_bounds__(256) void bf_kernel(const float* __restrict__ mix,
                                                 const float* __restrict__ wc,
                                                 float* __restrict__ out) {
    int idx = blockIdx.x * 256 + threadIdx.x;
    const int perN = TT * FF;
    if (idx >= NN * perN) return;
    int n = idx / perN;
    int rem = idx - n * perN;
    int t = rem / FF;
    int f = rem - t * FF;

    const float4* w4 = (const float4*)(wc + ((size_t)(n * FF + f)) * 16);
    float4 w0 = w4[0], w1 = w4[1], w2 = w4[2], w3 = w4[3];
    float wr[CC] = {w0.x, w0.z, w1.x, w1.z, w2.x, w2.z, w3.x, w3.z};
    float wi[CC] = {w0.y, w0.w, w1.y, w1.w, w2.y, w2.w, w3.y, w3.w};

    const float* base = mix + (size_t)n * (2 * CC * TT * FF) + t * FF + f;
    float Xr = 0.f, Xi = 0.f;
#pragma unroll
    for (int c = 0; c < CC; ++c) {
        float yr = base[c * TT * FF];
        float yi = base[(CC + c) * TT * FF];
        Xr += wr[c] * yr - wi[c] * yi;
        Xi += wr[c] * yi + wi[c] * yr;
    }
    out[((size_t)(n * 2 + 0) * TT + t) * FF + f] = Xr;
    out[((size_t)(n * 2 + 1) * TT + t) * FF + f] = Xi;
}

extern "C" void kernel_launch(void* const* d_in, const int* in_sizes, int n_in,
                              void* d_out, int out_size, void* d_ws, size_t ws_size,
                              hipStream_t stream) {
    const float* mixture = (const float*)d_in[0];
    const float* noise = (const float*)d_in[1];
    const float* steer = (const float*)d_in[2];
    float* out = (float*)d_out;

    float* partial = (float*)d_ws;
    size_t per_chunk = (size_t)NF * 64 * sizeof(float);
    size_t wc_bytes = (size_t)NF * 16 * sizeof(float);
    int ntc = 25;
    while (ntc > 1 && per_chunk * (size_t)ntc + wc_bytes > ws_size) --ntc;
    int tc = (TT + ntc - 1) / ntc;
    float* wcp = partial + (size_t)ntc * NF * 64;

    dim3 gcov((NF + 63) / 64, ntc);  // 33 x 25 = 825 blocks of 4 waves
    cov2_kernel<<<gcov, 256, 0, stream>>>(noise, partial, tc);
    solve2_kernel<<<NF / 4, 256, 0, stream>>>(partial, steer, wcp, ntc);
    int total = NN * TT * FF;
    bf_kernel<<<(total + 255) / 256, 256, 0, stream>>>(mixture, wcp, out);
}